// Round 1
// baseline (788.568 us; speedup 1.0000x reference)
//
#include <hip/hip_runtime.h>
#include <stdint.h>
#include <stddef.h>

#define B_SZ   2048
#define E_SZ   96
#define K_SZ   8
#define U_SZ   1024
#define EK     (E_SZ * K_SZ)           /* 768  */
#define KD     ((E_SZ + U_SZ) * K_SZ)  /* 8960 */
#define NZ     (4 * U_SZ)              /* 4096 */

typedef __bf16 bf16_t;
typedef __bf16 bf16x8 __attribute__((ext_vector_type(8)));
typedef __bf16 bf16x4 __attribute__((ext_vector_type(4)));
typedef float  f32x4  __attribute__((ext_vector_type(4)));

typedef __attribute__((address_space(3))) void       lds_void;
typedef const __attribute__((address_space(1))) void gbl_void;

__device__ __forceinline__ void gload16(const void* g, void* l) {
    __builtin_amdgcn_global_load_lds((gbl_void*)g, (lds_void*)l, 16, 0, 0);
}

// ---------------- pass 1: A = [x (x) cp | h (x) cp], split hi/lo bf16 ----------------
// A row length KD=8960; thread handles one (b, e-or-u) -> 8 k's (16B per array).
__global__ __launch_bounds__(256) void build_a_kernel(
    const float* __restrict__ inputs,   // (B, 104)
    const float* __restrict__ h_tm1,    // (B, 1024)
    bf16_t* __restrict__ Ah,
    bf16_t* __restrict__ Al)
{
    unsigned tid = blockIdx.x * 256u + threadIdx.x;   // exactly 2048*1120
    unsigned b   = tid / 1120u;
    unsigned i8  = tid - b * 1120u;

    const float* row = inputs + (size_t)b * (E_SZ + K_SZ);
    f32x4 cp0 = *(const f32x4*)(row + E_SZ);
    f32x4 cp1 = *(const f32x4*)(row + E_SZ + 4);
    float cp[8] = {cp0[0], cp0[1], cp0[2], cp0[3], cp1[0], cp1[1], cp1[2], cp1[3]};

    float base = (i8 < (unsigned)E_SZ) ? row[i8]
                                       : h_tm1[(size_t)b * U_SZ + (i8 - E_SZ)];
    bf16x8 hi, lo;
    #pragma unroll
    for (int k = 0; k < 8; ++k) {
        float  p = base * cp[k];
        bf16_t h = (bf16_t)p;
        float  r = p - (float)h;
        hi[k] = h;
        lo[k] = (bf16_t)r;
    }
    size_t o = (size_t)b * KD + (size_t)i8 * 8;
    *(bf16x8*)(Ah + o) = hi;
    *(bf16x8*)(Al + o) = lo;
}

// ---------------- pass 2: W (8960 x 4096 f32, two arrays) -> W^T hi/lo bf16 (4096 x 8960) ----------------
__global__ __launch_bounds__(256) void transpose_w_kernel(
    const float* __restrict__ bk,    // (768, 4096)
    const float* __restrict__ brk,   // (8192, 4096)
    bf16_t* __restrict__ Wth,
    bf16_t* __restrict__ Wtl)
{
    __shared__ float tile[64][65];
    int r0 = blockIdx.x * 64;        // 140 tiles along K (768 % 64 == 0, no straddle)
    int z0 = blockIdx.y * 64;        // 64 tiles along N
    const float* src = (r0 < EK) ? (bk + (size_t)r0 * NZ)
                                 : (brk + (size_t)(r0 - EK) * NZ);
    int t  = threadIdx.x;
    int rl = t >> 4;            // 0..15
    int c4 = (t & 15) * 4;      // 0..60

    #pragma unroll
    for (int i = 0; i < 4; ++i) {
        int r = rl + i * 16;
        f32x4 v = *(const f32x4*)(src + (size_t)r * NZ + z0 + c4);
        tile[r][c4 + 0] = v[0];
        tile[r][c4 + 1] = v[1];
        tile[r][c4 + 2] = v[2];
        tile[r][c4 + 3] = v[3];
    }
    __syncthreads();
    #pragma unroll
    for (int i = 0; i < 4; ++i) {
        int z = rl + i * 16;
        bf16x4 hi, lo;
        #pragma unroll
        for (int j = 0; j < 4; ++j) {
            float  f = tile[c4 + j][z];
            bf16_t h = (bf16_t)f;
            hi[j] = h;
            lo[j] = (bf16_t)(f - (float)h);
        }
        size_t o = (size_t)(z0 + z) * KD + r0 + c4;
        *(bf16x4*)(Wth + o) = hi;
        *(bf16x4*)(Wtl + o) = lo;
    }
}

// ---------------- pass 3: z = Ah*Wh + Ah*Wl + Al*Wh (+bias), fused LSTM epilogue ----------------
// 128x128 tile; columns c = gate*32 + j_local so each wave (32 rows x 128 cols)
// holds all 4 gates of a given j in the same lane across frags n, n+2, n+4, n+6.
__global__ __launch_bounds__(256) void basis_lstm_gemm_kernel(
    const bf16_t* __restrict__ Ah, const bf16_t* __restrict__ Al,
    const bf16_t* __restrict__ Wth, const bf16_t* __restrict__ Wtl,
    const float* __restrict__ bias, const float* __restrict__ c_tm1,
    float* __restrict__ out)
{
    __shared__ __align__(16) bf16_t sA[128 * 64];
    __shared__ __align__(16) bf16_t sW[128 * 64];

    // XCD-aware bijective swizzle (512 blocks = 8 * 64): blocks sharing jb land on one XCD
    int id  = blockIdx.x;
    int v   = (id & 7) * 64 + (id >> 3);
    int bm0 = (v & 15) * 128;       // row-tile (b)
    int jb0 = (v >> 4) * 32;        // 32 j-columns per block (x4 gates = 128 z-cols)

    int t    = threadIdx.x;
    int lane = t & 63;
    int w    = t >> 6;              // wave 0..3, rows [w*32, w*32+32)
    int fr   = lane & 15;
    int hi4  = lane >> 4;

    f32x4 acc[2][8];
    #pragma unroll
    for (int m = 0; m < 2; ++m)
        #pragma unroll
        for (int n = 0; n < 8; ++n)
            acc[m][n] = (f32x4){0.f, 0.f, 0.f, 0.f};

    #pragma unroll 1
    for (int p = 0; p < 3; ++p) {
        const bf16_t* As = (p == 2) ? Al : Ah;
        const bf16_t* Ws = (p == 1) ? Wtl : Wth;
        #pragma unroll 1
        for (int ks = 0; ks < 140; ++ks) {
            int ko = ks * 64;
            // stage A tile (128 rows x 64 k), swizzled SOURCE so linear LDS dest
            // reads back conflict-free: LDS chunk (row,c) holds global chunk c^(row&7)
            #pragma unroll
            for (int i = 0; i < 4; ++i) {
                int idx = i * 256 + t;
                int row = idx >> 3;
                int cc  = idx & 7;
                const bf16_t* g = As + (size_t)(bm0 + row) * KD + ko + ((cc ^ (row & 7)) << 3);
                gload16(g, &sA[idx * 8]);
            }
            // stage W tile: LDS row c -> z = (c>>5)*1024 + jb0 + (c&31)
            #pragma unroll
            for (int i = 0; i < 4; ++i) {
                int idx = i * 256 + t;
                int row = idx >> 3;
                int cc  = idx & 7;
                int z   = ((row >> 5) << 10) + jb0 + (row & 31);
                const bf16_t* g = Ws + (size_t)z * KD + ko + ((cc ^ (row & 7)) << 3);
                gload16(g, &sW[idx * 8]);
            }
            __syncthreads();   // compiler drains vmcnt before s_barrier
            #pragma unroll
            for (int kk = 0; kk < 2; ++kk) {
                bf16x8 af[2];
                #pragma unroll
                for (int m = 0; m < 2; ++m) {
                    int ra = w * 32 + m * 16 + fr;
                    af[m] = *(const bf16x8*)&sA[ra * 64 + (((kk * 4 + hi4) ^ (ra & 7)) << 3)];
                }
                #pragma unroll
                for (int n = 0; n < 8; ++n) {
                    int rw = n * 16 + fr;
                    bf16x8 wf = *(const bf16x8*)&sW[rw * 64 + (((kk * 4 + hi4) ^ (rw & 7)) << 3)];
                    acc[0][n] = __builtin_amdgcn_mfma_f32_16x16x32_bf16(af[0], wf, acc[0][n], 0, 0, 0);
                    acc[1][n] = __builtin_amdgcn_mfma_f32_16x16x32_bf16(af[1], wf, acc[1][n], 0, 0, 0);
                }
            }
            __syncthreads();
        }
    }

    // fused LSTM epilogue: acc row = b (C/D: row=(lane>>4)*4+reg), col c = n*16 + (lane&15)
    float* out_h = out;
    float* out_c = out + (size_t)B_SZ * U_SZ;
    #pragma unroll
    for (int m = 0; m < 2; ++m) {
        #pragma unroll
        for (int jn = 0; jn < 2; ++jn) {
            int jg = jb0 + jn * 16 + fr;
            float b0 = bias[jg];
            float b1 = bias[U_SZ + jg];
            float b2 = bias[2 * U_SZ + jg];
            float b3 = bias[3 * U_SZ + jg];
            #pragma unroll
            for (int q = 0; q < 4; ++q) {
                int   br = bm0 + w * 32 + m * 16 + hi4 * 4 + q;
                float zi = acc[m][0 + jn][q] + b0;
                float zf = acc[m][2 + jn][q] + b1;
                float zc = acc[m][4 + jn][q] + b2;
                float zo = acc[m][6 + jn][q] + b3;
                float ig = 1.f / (1.f + __expf(-zi));
                float fg = 1.f / (1.f + __expf(-zf));
                float og = 1.f / (1.f + __expf(-zo));
                float cn = fg * c_tm1[(size_t)br * U_SZ + jg] + ig * tanhf(zc);
                float hn = og * tanhf(cn);
                out_h[(size_t)br * U_SZ + jg] = hn;
                out_c[(size_t)br * U_SZ + jg] = cn;
            }
        }
    }
}

extern "C" void kernel_launch(void* const* d_in, const int* in_sizes, int n_in,
                              void* d_out, int out_size, void* d_ws, size_t ws_size,
                              hipStream_t stream) {
    const float* inputs = (const float*)d_in[0];
    const float* h_tm1  = (const float*)d_in[1];
    const float* c_tm1  = (const float*)d_in[2];
    const float* bk     = (const float*)d_in[3];
    const float* brk    = (const float*)d_in[4];
    const float* bias   = (const float*)d_in[5];

    // workspace layout (bytes):
    //   Ah : 2048*8960*2 = 36,700,160
    //   Al : 36,700,160
    //   Wth: 4096*8960*2 = 73,400,320
    //   Wtl: 73,400,320     total = 220,200,960
    char*   ws  = (char*)d_ws;
    bf16_t* Ah  = (bf16_t*)(ws);
    bf16_t* Al  = (bf16_t*)(ws + 36700160u);
    bf16_t* Wth = (bf16_t*)(ws + 2u * 36700160u);
    bf16_t* Wtl = (bf16_t*)(ws + 2u * 36700160u + 73400320u);

    hipLaunchKernelGGL(build_a_kernel, dim3(8960), dim3(256), 0, stream,
                       inputs, h_tm1, Ah, Al);
    hipLaunchKernelGGL(transpose_w_kernel, dim3(140, 64), dim3(256), 0, stream,
                       bk, brk, Wth, Wtl);
    hipLaunchKernelGGL(basis_lstm_gemm_kernel, dim3(512), dim3(256), 0, stream,
                       Ah, Al, Wth, Wtl, bias, c_tm1, (float*)d_out);
}

// Round 2
// 677.935 us; speedup vs baseline: 1.1632x; 1.1632x over previous
//
#include <hip/hip_runtime.h>
#include <stdint.h>
#include <stddef.h>

#define B_SZ   2048
#define E_SZ   96
#define K_SZ   8
#define U_SZ   1024
#define EK     (E_SZ * K_SZ)           /* 768  */
#define KD     ((E_SZ + U_SZ) * K_SZ)  /* 8960 */
#define NZ     (4 * U_SZ)              /* 4096 */

typedef __bf16 bf16_t;
typedef __bf16 bf16x8 __attribute__((ext_vector_type(8)));
typedef float  f32x4  __attribute__((ext_vector_type(4)));

typedef __attribute__((address_space(3))) void       lds_void;
typedef const __attribute__((address_space(1))) void gbl_void;

__device__ __forceinline__ void gload16(const void* g, void* l) {
    __builtin_amdgcn_global_load_lds((gbl_void*)g, (lds_void*)l, 16, 0, 0);
}

// ---------------- pass 1: A = [x (x) cp | h (x) cp], split hi/lo bf16 ----------------
__global__ __launch_bounds__(256) void build_a_kernel(
    const float* __restrict__ inputs,   // (B, 104)
    const float* __restrict__ h_tm1,    // (B, 1024)
    bf16_t* __restrict__ Ah,
    bf16_t* __restrict__ Al)
{
    unsigned tid = blockIdx.x * 256u + threadIdx.x;   // exactly 2048*1120
    unsigned b   = tid / 1120u;
    unsigned i8  = tid - b * 1120u;

    const float* row = inputs + (size_t)b * (E_SZ + K_SZ);
    f32x4 cp0 = *(const f32x4*)(row + E_SZ);
    f32x4 cp1 = *(const f32x4*)(row + E_SZ + 4);
    float cp[8] = {cp0[0], cp0[1], cp0[2], cp0[3], cp1[0], cp1[1], cp1[2], cp1[3]};

    float base = (i8 < (unsigned)E_SZ) ? row[i8]
                                       : h_tm1[(size_t)b * U_SZ + (i8 - E_SZ)];
    bf16x8 hi, lo;
    #pragma unroll
    for (int k = 0; k < 8; ++k) {
        float  p = base * cp[k];
        bf16_t h = (bf16_t)p;
        float  r = p - (float)h;
        hi[k] = h;
        lo[k] = (bf16_t)r;
    }
    size_t o = (size_t)b * KD + (size_t)i8 * 8;
    *(bf16x8*)(Ah + o) = hi;
    *(bf16x8*)(Al + o) = lo;
}

// ---------------- pass 2: W (8960 x 4096 f32) -> W^T hi/lo bf16 (4096 x 8960) ----------------
__global__ __launch_bounds__(256) void transpose_w_kernel(
    const float* __restrict__ bk,    // (768, 4096)
    const float* __restrict__ brk,   // (8192, 4096)
    bf16_t* __restrict__ Wth,
    bf16_t* __restrict__ Wtl)
{
    __shared__ float tile[64][65];
    int r0 = blockIdx.x * 64;        // 140 tiles along K (768 % 64 == 0, no straddle)
    int z0 = blockIdx.y * 64;
    const float* src = (r0 < EK) ? (bk + (size_t)r0 * NZ)
                                 : (brk + (size_t)(r0 - EK) * NZ);
    int t  = threadIdx.x;
    int rl = t >> 4;
    int c4 = (t & 15) * 4;

    #pragma unroll
    for (int i = 0; i < 4; ++i) {
        int r = rl + i * 16;
        f32x4 v = *(const f32x4*)(src + (size_t)r * NZ + z0 + c4);
        tile[r][c4 + 0] = v[0];
        tile[r][c4 + 1] = v[1];
        tile[r][c4 + 2] = v[2];
        tile[r][c4 + 3] = v[3];
    }
    __syncthreads();
    int zl = t >> 3;             // 0..31
    int c8 = (t & 7) * 8;        // 0..56
    #pragma unroll
    for (int i = 0; i < 2; ++i) {
        int z = zl + i * 32;
        bf16x8 hi, lo;
        #pragma unroll
        for (int j = 0; j < 8; ++j) {
            float  f = tile[c8 + j][z];   // 2-way bank max (free)
            bf16_t h = (bf16_t)f;
            hi[j] = h;
            lo[j] = (bf16_t)(f - (float)h);
        }
        size_t o = (size_t)(z0 + z) * KD + r0 + c8;
        *(bf16x8*)(Wth + o) = hi;    // 16B/lane stores
        *(bf16x8*)(Wtl + o) = lo;
    }
}

// ---------------- pass 3: fused 3-product GEMM + LSTM epilogue ----------------
// BM=256 x BN=128 (32 j * 4 gates), BK=32, 8 waves (4M x 2N), wave tile 64x64.
// Per K-tile stage Ah,Al,Wh,Wl once; compute hh, hl (reuse Ah frags), lh (reuse Wh frags).
// 3-deep circular LDS buffer, counted vmcnt(6), raw barriers, setprio around MFMA.
#define BM 256
#define BN 128
#define BK 32
#define NT 280                      /* 8960/32 */
#define ABYTES (BM * BK * 2)        /* 16384 */
#define WBYTES (BN * BK * 2)        /* 8192  */
#define BUFB   (2 * ABYTES + 2 * WBYTES)  /* 49152 */

__global__ __launch_bounds__(512, 2) void basis_lstm_gemm_kernel(
    const bf16_t* __restrict__ Ah, const bf16_t* __restrict__ Al,
    const bf16_t* __restrict__ Wth, const bf16_t* __restrict__ Wtl,
    const float* __restrict__ bias, const float* __restrict__ c_tm1,
    float* __restrict__ out)
{
    extern __shared__ __align__(16) char smem[];

    // XCD swizzle: 256 blocks = 8 XCD x 32; each XCD: all 8 bm x 4 jb tiles
    int id  = blockIdx.x;
    int v   = (id & 7) * 32 + (id >> 3);
    int bm0 = (v & 7) * BM;
    int jb0 = (v >> 3) * 32;        // 32 j-columns per block

    int t    = threadIdx.x;
    int lane = t & 63;
    int w    = t >> 6;
    int wm   = w >> 1;              // 0..3 -> rows [wm*64, +64)
    int wn   = w & 1;               // 0..1 -> cols [wn*64, +64)
    int fr   = lane & 15;
    int hi4  = lane >> 4;

    f32x4 acc[4][4];
    #pragma unroll
    for (int m = 0; m < 4; ++m)
        #pragma unroll
        for (int n = 0; n < 4; ++n)
            acc[m][n] = (f32x4){0.f, 0.f, 0.f, 0.f};

    // ---- staging: 6 gload16/thread/tile; LDS slot (row,cc) holds global chunk cc^((row>>1)&3)
    auto stage = [&](int buf, int kt) {
        char* base = smem + buf * BUFB;
        int   ko   = kt * BK;
        #pragma unroll
        for (int i = 0; i < 2; ++i) {
            int q   = i * 512 + t;          // 0..1023
            int row = q >> 2;
            int cc  = q & 3;
            size_t off = (size_t)(bm0 + row) * KD + ko + ((cc ^ ((row >> 1) & 3)) << 3);
            gload16(Ah + off, base + q * 16);
            gload16(Al + off, base + ABYTES + q * 16);
        }
        {
            int q  = t;                     // 0..511
            int c  = q >> 2;
            int cc = q & 3;
            int z  = (((c >> 4) & 3) << 10) + jb0 + ((c >> 6) << 4) + (c & 15);
            size_t off = (size_t)z * KD + ko + ((cc ^ ((c >> 1) & 3)) << 3);
            gload16(Wth + off, base + 2 * ABYTES + q * 16);
            gload16(Wtl + off, base + 2 * ABYTES + WBYTES + q * 16);
        }
    };

    auto compute = [&](int buf) {
        const char*   base = smem + buf * BUFB;
        const bf16_t* sAh  = (const bf16_t*)base;
        const bf16_t* sAl  = (const bf16_t*)(base + ABYTES);
        const bf16_t* sWh  = (const bf16_t*)(base + 2 * ABYTES);
        const bf16_t* sWl  = (const bf16_t*)(base + 2 * ABYTES + WBYTES);
        bf16x8 afh[4], wfh[4], xf[4];
        #pragma unroll
        for (int m = 0; m < 4; ++m) {
            int ra = wm * 64 + m * 16 + fr;
            afh[m] = *(const bf16x8*)&sAh[ra * 32 + ((hi4 ^ ((ra >> 1) & 3)) << 3)];
        }
        #pragma unroll
        for (int n = 0; n < 4; ++n) {
            int c = wn * 64 + n * 16 + fr;
            wfh[n] = *(const bf16x8*)&sWh[c * 32 + ((hi4 ^ ((c >> 1) & 3)) << 3)];
        }
        __builtin_amdgcn_s_setprio(1);
        #pragma unroll
        for (int m = 0; m < 4; ++m)
            #pragma unroll
            for (int n = 0; n < 4; ++n)
                acc[m][n] = __builtin_amdgcn_mfma_f32_16x16x32_bf16(afh[m], wfh[n], acc[m][n], 0, 0, 0);
        __builtin_amdgcn_s_setprio(0);
        #pragma unroll
        for (int n = 0; n < 4; ++n) {
            int c = wn * 64 + n * 16 + fr;
            xf[n] = *(const bf16x8*)&sWl[c * 32 + ((hi4 ^ ((c >> 1) & 3)) << 3)];
        }
        __builtin_amdgcn_s_setprio(1);
        #pragma unroll
        for (int m = 0; m < 4; ++m)
            #pragma unroll
            for (int n = 0; n < 4; ++n)
                acc[m][n] = __builtin_amdgcn_mfma_f32_16x16x32_bf16(afh[m], xf[n], acc[m][n], 0, 0, 0);
        __builtin_amdgcn_s_setprio(0);
        #pragma unroll
        for (int m = 0; m < 4; ++m) {
            int ra = wm * 64 + m * 16 + fr;
            xf[m] = *(const bf16x8*)&sAl[ra * 32 + ((hi4 ^ ((ra >> 1) & 3)) << 3)];
        }
        __builtin_amdgcn_s_setprio(1);
        #pragma unroll
        for (int m = 0; m < 4; ++m)
            #pragma unroll
            for (int n = 0; n < 4; ++n)
                acc[m][n] = __builtin_amdgcn_mfma_f32_16x16x32_bf16(xf[m], wfh[n], acc[m][n], 0, 0, 0);
        __builtin_amdgcn_s_setprio(0);
    };

    stage(0, 0);
    stage(1, 1);
    asm volatile("s_waitcnt vmcnt(6)" ::: "memory");   // tile 0 landed
    __builtin_amdgcn_s_barrier();

    for (int kt = 0; kt < NT; ++kt) {
        if (kt + 2 < NT) stage((kt + 2) % 3, kt + 2);
        compute(kt % 3);
        if (kt + 2 < NT) {
            asm volatile("s_waitcnt vmcnt(6)" ::: "memory");   // tile kt+1 landed
        } else {
            asm volatile("s_waitcnt vmcnt(0)" ::: "memory");
        }
        __builtin_amdgcn_s_barrier();
    }

    // ---- fused LSTM epilogue: each wave holds all 4 gates of j = jb0 + wn*16 + fr
    float* out_h = out;
    float* out_c = out + (size_t)B_SZ * U_SZ;
    int   jg = jb0 + wn * 16 + fr;
    float b0 = bias[jg];
    float b1 = bias[U_SZ + jg];
    float b2 = bias[2 * U_SZ + jg];
    float b3 = bias[3 * U_SZ + jg];
    #pragma unroll
    for (int m = 0; m < 4; ++m) {
        #pragma unroll
        for (int q = 0; q < 4; ++q) {
            int   br = bm0 + wm * 64 + m * 16 + hi4 * 4 + q;
            float zi = acc[m][0][q] + b0;
            float zf = acc[m][1][q] + b1;
            float zc = acc[m][2][q] + b2;
            float zo = acc[m][3][q] + b3;
            float ig = 1.f / (1.f + __expf(-zi));
            float fg = 1.f / (1.f + __expf(-zf));
            float og = 1.f / (1.f + __expf(-zo));
            float cn = fg * c_tm1[(size_t)br * U_SZ + jg] + ig * tanhf(zc);
            float hn = og * tanhf(cn);
            out_h[(size_t)br * U_SZ + jg] = hn;
            out_c[(size_t)br * U_SZ + jg] = cn;
        }
    }
}

extern "C" void kernel_launch(void* const* d_in, const int* in_sizes, int n_in,
                              void* d_out, int out_size, void* d_ws, size_t ws_size,
                              hipStream_t stream) {
    const float* inputs = (const float*)d_in[0];
    const float* h_tm1  = (const float*)d_in[1];
    const float* c_tm1  = (const float*)d_in[2];
    const float* bk     = (const float*)d_in[3];
    const float* brk    = (const float*)d_in[4];
    const float* bias   = (const float*)d_in[5];

    // workspace: Ah 36,700,160 | Al 36,700,160 | Wth 73,400,320 | Wtl 73,400,320
    char*   ws  = (char*)d_ws;
    bf16_t* Ah  = (bf16_t*)(ws);
    bf16_t* Al  = (bf16_t*)(ws + 36700160u);
    bf16_t* Wth = (bf16_t*)(ws + 2u * 36700160u);
    bf16_t* Wtl = (bf16_t*)(ws + 2u * 36700160u + 73400320u);

    hipFuncSetAttribute((const void*)basis_lstm_gemm_kernel,
                        hipFuncAttributeMaxDynamicSharedMemorySize, 3 * BUFB);

    hipLaunchKernelGGL(build_a_kernel, dim3(8960), dim3(256), 0, stream,
                       inputs, h_tm1, Ah, Al);
    hipLaunchKernelGGL(transpose_w_kernel, dim3(140, 64), dim3(256), 0, stream,
                       bk, brk, Wth, Wtl);
    hipLaunchKernelGGL(basis_lstm_gemm_kernel, dim3(256), dim3(512), 3 * BUFB, stream,
                       Ah, Al, Wth, Wtl, bias, c_tm1, (float*)d_out);
}

// Round 3
// 400.950 us; speedup vs baseline: 1.9667x; 1.6908x over previous
//
#include <hip/hip_runtime.h>
#include <stdint.h>
#include <stddef.h>

#define B_SZ   2048
#define E_SZ   96
#define K_SZ   8
#define U_SZ   1024
#define EK     (E_SZ * K_SZ)           /* 768  */
#define KD     ((E_SZ + U_SZ) * K_SZ)  /* 8960 */
#define NZ     (4 * U_SZ)              /* 4096 */

typedef _Float16 f16_t;
typedef _Float16 f16x8 __attribute__((ext_vector_type(8)));
typedef float    f32x4 __attribute__((ext_vector_type(4)));

typedef __attribute__((address_space(3))) void       lds_void;
typedef const __attribute__((address_space(1))) void gbl_void;

__device__ __forceinline__ void gload16(const void* g, void* l) {
    __builtin_amdgcn_global_load_lds((gbl_void*)g, (lds_void*)l, 16, 0, 0);
}

// ---------------- pass 1: A = [x (x) cp | h (x) cp] -> f16 ----------------
__global__ __launch_bounds__(256) void build_a_kernel(
    const float* __restrict__ inputs,   // (B, 104)
    const float* __restrict__ h_tm1,    // (B, 1024)
    f16_t* __restrict__ Ah)
{
    unsigned tid = blockIdx.x * 256u + threadIdx.x;   // exactly 2048*1120
    unsigned b   = tid / 1120u;
    unsigned i8  = tid - b * 1120u;

    const float* row = inputs + (size_t)b * (E_SZ + K_SZ);
    f32x4 cp0 = *(const f32x4*)(row + E_SZ);
    f32x4 cp1 = *(const f32x4*)(row + E_SZ + 4);
    float cp[8] = {cp0[0], cp0[1], cp0[2], cp0[3], cp1[0], cp1[1], cp1[2], cp1[3]};

    float base = (i8 < (unsigned)E_SZ) ? row[i8]
                                       : h_tm1[(size_t)b * U_SZ + (i8 - E_SZ)];
    f16x8 hi;
    #pragma unroll
    for (int k = 0; k < 8; ++k)
        hi[k] = (f16_t)(base * cp[k]);
    *(f16x8*)(Ah + (size_t)b * KD + (size_t)i8 * 8) = hi;
}

// ---------------- pass 2: W (8960 x 4096 f32) -> W^T f16 (4096 x 8960) ----------------
__global__ __launch_bounds__(256) void transpose_w_kernel(
    const float* __restrict__ bk,    // (768, 4096)
    const float* __restrict__ brk,   // (8192, 4096)
    f16_t* __restrict__ Wth)
{
    __shared__ float tile[64][65];
    int r0 = blockIdx.x * 64;        // 140 tiles along K (768 % 64 == 0, no straddle)
    int z0 = blockIdx.y * 64;
    const float* src = (r0 < EK) ? (bk + (size_t)r0 * NZ)
                                 : (brk + (size_t)(r0 - EK) * NZ);
    int t  = threadIdx.x;
    int rl = t >> 4;
    int c4 = (t & 15) * 4;

    #pragma unroll
    for (int i = 0; i < 4; ++i) {
        int r = rl + i * 16;
        f32x4 v = *(const f32x4*)(src + (size_t)r * NZ + z0 + c4);
        tile[r][c4 + 0] = v[0];
        tile[r][c4 + 1] = v[1];
        tile[r][c4 + 2] = v[2];
        tile[r][c4 + 3] = v[3];
    }
    __syncthreads();
    int zl = t >> 3;             // 0..31
    int c8 = (t & 7) * 8;        // 0..56
    #pragma unroll
    for (int i = 0; i < 2; ++i) {
        int z = zl + i * 32;
        f16x8 hi;
        #pragma unroll
        for (int j = 0; j < 8; ++j)
            hi[j] = (f16_t)tile[c8 + j][z];   // 2-way bank max (free)
        *(f16x8*)(Wth + (size_t)(z0 + z) * KD + r0 + c8) = hi;
    }
}

// ---------------- pass 3: single-pass f16 GEMM + fused LSTM epilogue ----------------
// BM=256 x BN=128 (32 j * 4 gates), BK=64, 8 waves (4m x 2n), wave tile 64x64.
// 3-deep circular LDS buffer (144 KB), counted vmcnt(6), 2 phases per K-tile.
#define BM 256
#define BN 128
#define BK 64
#define NT 140                      /* 8960/64 */
#define ABYTES (BM * BK * 2)        /* 32768 */
#define WBYTES (BN * BK * 2)        /* 16384 */
#define BUFB   (ABYTES + WBYTES)    /* 49152 */

__global__ __launch_bounds__(512, 2) void basis_lstm_gemm_kernel(
    const f16_t* __restrict__ Ah, const f16_t* __restrict__ Wth,
    const float* __restrict__ bias, const float* __restrict__ c_tm1,
    float* __restrict__ out)
{
    extern __shared__ __align__(16) char smem[];

    // XCD swizzle: 256 blocks = 8 XCD x 32; jb-major within an XCD for W L2-reuse
    int id  = blockIdx.x;
    int v   = (id & 7) * 32 + (id >> 3);
    int bm0 = (v & 7) * BM;
    int jb0 = (v >> 3) * 32;        // 32 j-columns per block

    int t    = threadIdx.x;
    int lane = t & 63;
    int w    = t >> 6;
    int wm   = w >> 1;              // 0..3 -> rows [wm*64, +64)
    int wn   = w & 1;               // 0..1 -> cols [wn*64, +64)
    int fr   = lane & 15;
    int hi4  = lane >> 4;

    f32x4 acc[4][4];
    #pragma unroll
    for (int m = 0; m < 4; ++m)
        #pragma unroll
        for (int n = 0; n < 4; ++n)
            acc[m][n] = (f32x4){0.f, 0.f, 0.f, 0.f};

    // stage part: part 0 -> A chunks {t, 512+t} + B chunk {t};
    //             part 1 -> A chunks {1024+t, 1536+t} + B chunk {512+t}
    // LDS slot (row, cc) holds global chunk cc ^ (row&7)  (rows are 128B = 8 chunks)
    auto stage_part = [&](int buf, int kt, int part) {
        char* base = smem + buf * BUFB;
        int   ko   = kt * BK;
        #pragma unroll
        for (int i = 0; i < 2; ++i) {
            int q   = (part * 2 + i) * 512 + t;   // 0..2047
            int row = q >> 3;
            int cc  = q & 7;
            size_t off = (size_t)(bm0 + row) * KD + ko + ((cc ^ (row & 7)) << 3);
            gload16(Ah + off, base + q * 16);
        }
        {
            int q  = part * 512 + t;              // 0..1023
            int c  = q >> 3;
            int cc = q & 7;
            int z  = (((c >> 4) & 3) << 10) + jb0 + ((c >> 6) << 4) + (c & 15);
            size_t off = (size_t)z * KD + ko + ((cc ^ (c & 7)) << 3);
            gload16(Wth + off, base + ABYTES + q * 16);
        }
    };

    auto phase = [&](int buf, int kk, int kt2, bool do_stage) {
        const char* base = smem + buf * BUFB;
        f16x8 af[4], wf[4];
        #pragma unroll
        for (int m = 0; m < 4; ++m) {
            int ra = wm * 64 + m * 16 + fr;
            af[m] = *(const f16x8*)(base + ra * 128 + (((kk * 4 + hi4) ^ (ra & 7)) << 4));
        }
        #pragma unroll
        for (int n = 0; n < 4; ++n) {
            int rc = wn * 64 + n * 16 + fr;
            wf[n] = *(const f16x8*)(base + ABYTES + rc * 128 + (((kk * 4 + hi4) ^ (rc & 7)) << 4));
        }
        if (do_stage) stage_part((kt2 % 3), kt2, kk);
        __builtin_amdgcn_s_barrier();
        asm volatile("s_waitcnt lgkmcnt(0)" ::: "memory");
        __builtin_amdgcn_s_setprio(1);
        #pragma unroll
        for (int m = 0; m < 4; ++m)
            #pragma unroll
            for (int n = 0; n < 4; ++n)
                acc[m][n] = __builtin_amdgcn_mfma_f32_16x16x32_f16(af[m], wf[n], acc[m][n], 0, 0, 0);
        __builtin_amdgcn_s_setprio(0);
    };

    stage_part(0, 0, 0); stage_part(0, 0, 1);
    stage_part(1, 1, 0); stage_part(1, 1, 1);
    asm volatile("s_waitcnt vmcnt(6)" ::: "memory");   // tile 0 landed
    __builtin_amdgcn_s_barrier();

    for (int kt = 0; kt < NT; ++kt) {
        bool st = (kt + 2 < NT);
        phase(kt % 3, 0, kt + 2, st);
        __builtin_amdgcn_s_barrier();
        phase(kt % 3, 1, kt + 2, st);
        if (st) {
            asm volatile("s_waitcnt vmcnt(6)" ::: "memory");   // tile kt+1 landed
        } else {
            asm volatile("s_waitcnt vmcnt(0)" ::: "memory");
        }
        __builtin_amdgcn_s_barrier();
    }

    // ---- fused LSTM epilogue: acc[m][n] -> gate n, j = jb0 + wn*16 + fr
    float* out_h = out;
    float* out_c = out + (size_t)B_SZ * U_SZ;
    int   jg = jb0 + wn * 16 + fr;
    float b0 = bias[jg];
    float b1 = bias[U_SZ + jg];
    float b2 = bias[2 * U_SZ + jg];
    float b3 = bias[3 * U_SZ + jg];
    #pragma unroll
    for (int m = 0; m < 4; ++m) {
        #pragma unroll
        for (int q = 0; q < 4; ++q) {
            int   br = bm0 + wm * 64 + m * 16 + hi4 * 4 + q;
            float zi = acc[m][0][q] + b0;
            float zf = acc[m][1][q] + b1;
            float zc = acc[m][2][q] + b2;
            float zo = acc[m][3][q] + b3;
            float ig = 1.f / (1.f + __expf(-zi));
            float fg = 1.f / (1.f + __expf(-zf));
            float og = 1.f / (1.f + __expf(-zo));
            float cn = fg * c_tm1[(size_t)br * U_SZ + jg] + ig * tanhf(zc);
            float hn = og * tanhf(cn);
            out_h[(size_t)br * U_SZ + jg] = hn;
            out_c[(size_t)br * U_SZ + jg] = cn;
        }
    }
}

extern "C" void kernel_launch(void* const* d_in, const int* in_sizes, int n_in,
                              void* d_out, int out_size, void* d_ws, size_t ws_size,
                              hipStream_t stream) {
    const float* inputs = (const float*)d_in[0];
    const float* h_tm1  = (const float*)d_in[1];
    const float* c_tm1  = (const float*)d_in[2];
    const float* bk     = (const float*)d_in[3];
    const float* brk    = (const float*)d_in[4];
    const float* bias   = (const float*)d_in[5];

    // workspace: Ah 36,700,160 B | Wth 73,400,320 B  (total 110 MB, L3-resident)
    char*  ws  = (char*)d_ws;
    f16_t* Ah  = (f16_t*)(ws);
    f16_t* Wth = (f16_t*)(ws + 36700160u);

    hipFuncSetAttribute((const void*)basis_lstm_gemm_kernel,
                        hipFuncAttributeMaxDynamicSharedMemorySize, 3 * BUFB);

    hipLaunchKernelGGL(build_a_kernel, dim3(8960), dim3(256), 0, stream,
                       inputs, h_tm1, Ah);
    hipLaunchKernelGGL(transpose_w_kernel, dim3(140, 64), dim3(256), 0, stream,
                       bk, brk, Wth);
    hipLaunchKernelGGL(basis_lstm_gemm_kernel, dim3(256), dim3(512), 3 * BUFB, stream,
                       Ah, Wth, bias, c_tm1, (float*)d_out);
}